// Round 4
// baseline (291.899 us; speedup 1.0000x reference)
//
#include <hip/hip_runtime.h>
#include <hip/hip_bf16.h>

#define NN      50000
#define INDIM   512
#define HIDDEN  256
#define NE      800000
#define BIASF   0.0001f

typedef __attribute__((ext_vector_type(4))) float  f32x4;
typedef __attribute__((ext_vector_type(4))) __bf16 bf16x4;
typedef __attribute__((ext_vector_type(8))) __bf16 bf16x8;

// ---------------------------------------------------------------------------
// prep: blocks 0..31 : Wtb[n][k] = (bf16)W_emb[k][n] via coalesced LDS transpose
//       block  32    : w_sym[j] = 0.5*(We[j]+We[j+256])
// ---------------------------------------------------------------------------
__global__ __launch_bounds__(256) void prep_kernel(const float* __restrict__ W_emb,
                                                   const float* __restrict__ W_edge,
                                                   __bf16* __restrict__ Wtb,
                                                   float* __restrict__ w_sym) {
    const int b   = blockIdx.x;
    const int tid = threadIdx.x;
    if (b < 32) {
        __shared__ float t[64 * 65];
        const int kt = (b >> 2) * 64;
        const int nt = (b & 3) * 64;
        const int rr = tid >> 4;           // 0..15
        const int cc = (tid & 15) * 4;     // 0..60
#pragma unroll
        for (int p = 0; p < 4; ++p) {
            int r = p * 16 + rr;
            f32x4 v = *(const f32x4*)&W_emb[(size_t)(kt + r) * HIDDEN + nt + cc];
            t[(cc + 0) * 65 + r] = v[0];
            t[(cc + 1) * 65 + r] = v[1];
            t[(cc + 2) * 65 + r] = v[2];
            t[(cc + 3) * 65 + r] = v[3];
        }
        __syncthreads();
#pragma unroll
        for (int p = 0; p < 4; ++p) {
            int n = p * 16 + rr;
            bf16x4 o;
            o[0] = (__bf16)t[n * 65 + cc + 0];
            o[1] = (__bf16)t[n * 65 + cc + 1];
            o[2] = (__bf16)t[n * 65 + cc + 2];
            o[3] = (__bf16)t[n * 65 + cc + 3];
            *(bf16x4*)&Wtb[(size_t)(nt + n) * INDIM + kt + cc] = o;
        }
    } else {
        w_sym[tid] = 0.5f * (W_edge[tid] + W_edge[tid + HIDDEN]);
    }
}

// ---------------------------------------------------------------------------
// gemm_g v5: barrier-free per-wave streaming. Post-mortem of v2-v4: the
// LDS-staged, barrier-coupled structure stalled ~40us beyond its pipe model
// across 3 structural fixes (occupancy 2x, vmcnt-poison fix) — the 4-barrier
// x 8-wave convoy with 2 blocks/CU was the un-modeled cost. v5 removes ALL
// intra-block coupling: no LDS, no __syncthreads. Each wave owns 16 rows
// (50000 = 3125 x 16, no tail) and computes all 256 cols; A-frags are
// MFMA-shaped directly from global (row=ml, kslice=kq — v4-verified operand
// layout), B from L2-hot 256KB Wtb (strided dwordx4 = 16 full 64B lines per
// instr). Resource model: A 102MB once (~16us HBM/L3) + B 800MB L2 (~22us
// at 36.9 TB/s) + MFMA 6us, overlapped -> ~25us, nothing to convoy on.
// vmcnt in-order discipline by construction: consume order == issue order,
// every wait leaves >=8 B-loads + next-kstep A in flight; A prefetched one
// kstep ahead, residue hidden by 3 waves/SIMD of independent work.
// Regs: acc 64 + bA/bB 64 + A 16 + misc ~16 -> launch_bounds(256,3) cap 170.
//   g[m] = sum_n relu(emb[m]@W[:,n] + b[n]) * w_sym[n]
// ---------------------------------------------------------------------------
__global__ __launch_bounds__(256, 3) void gemm_g_kernel(const float* __restrict__ A,
                                                        const __bf16* __restrict__ Wtb,
                                                        const float* __restrict__ bias,
                                                        const float* __restrict__ w_sym,
                                                        float* __restrict__ g) {
    const int gw = (blockIdx.x << 2) + (threadIdx.x >> 6);   // global wave id
    if (gw >= 3125) return;                                  // no barriers below
    const int lane = threadIdx.x & 63;
    const int ml   = lane & 15;                              // A row / B col / D col
    const int kq   = lane >> 4;                              // k-slice (x8 elems)
    const int m0   = gw * 16;                                // rows m0..m0+15

    f32x4 acc[16];
#pragma unroll
    for (int j = 0; j < 16; ++j) acc[j] = (f32x4)0.0f;

    const float*  ap  = A   + (size_t)(m0 + ml) * INDIM + kq * 8;
    const __bf16* wpm = Wtb + (size_t)ml * INDIM + kq * 8;   // col ml, +j*16 cols = +j*8192

    bf16x8 bA[8], bB[8];
    f32x4  a0c, a1c, a0n, a1n;

    // prologue: kstep 0 A + first col-half B
    a0c = *(const f32x4*)(ap);
    a1c = *(const f32x4*)(ap + 4);
#pragma unroll
    for (int j = 0; j < 8; ++j)
        bA[j] = *(const bf16x8*)(wpm + j * 8192);

#pragma unroll
    for (int ks = 0; ks < 16; ++ks) {
        // issue B col-half 2 for this kstep (older than everything below)
#pragma unroll
        for (int j = 0; j < 8; ++j)
            bB[j] = *(const bf16x8*)(wpm + 65536 + j * 8192 + ks * 32);
        // issue next-kstep A early: HBM latency spans the two MFMA phases
        if (ks < 15) {
            a0n = *(const f32x4*)(ap + (ks + 1) * 32);
            a1n = *(const f32x4*)(ap + (ks + 1) * 32 + 4);
        }
        // cvt current A (loaded last iteration -> oldest outstanding or retired)
        bf16x8 af;
        af[0] = (__bf16)a0c[0]; af[1] = (__bf16)a0c[1];
        af[2] = (__bf16)a0c[2]; af[3] = (__bf16)a0c[3];
        af[4] = (__bf16)a1c[0]; af[5] = (__bf16)a1c[1];
        af[6] = (__bf16)a1c[2]; af[7] = (__bf16)a1c[3];
        // MFMA col-half 1: bA(ks) already resident; bB/aN keep flying
#pragma unroll
        for (int j = 0; j < 8; ++j)
            acc[j] = __builtin_amdgcn_mfma_f32_16x16x32_bf16(af, bA[j], acc[j], 0, 0, 0);
        // prefetch next-kstep B col-half 1 (youngest)
        if (ks < 15) {
#pragma unroll
            for (int j = 0; j < 8; ++j)
                bA[j] = *(const bf16x8*)(wpm + j * 8192 + (ks + 1) * 32);
        }
        // MFMA col-half 2: waits bB only (older than bA-next/aN) -> they fly on
#pragma unroll
        for (int j = 0; j < 8; ++j)
            acc[8 + j] = __builtin_amdgcn_mfma_f32_16x16x32_bf16(af, bB[j], acc[8 + j], 0, 0, 0);
        a0c = a0n; a1c = a1n;
    }

    // ---- epilogue: relu + dot w_sym across 256 cols, reduce over ml lanes ----
    // D layout: col = ml, row = kq*4 + r [m89/m91, v4-verified]
    float wsv[16], bcv[16];
#pragma unroll
    for (int j = 0; j < 16; ++j) {
        wsv[j] = w_sym[j * 16 + ml];
        bcv[j] = bias[j * 16 + ml];
    }
#pragma unroll
    for (int r = 0; r < 4; ++r) {
        float s = 0.0f;
#pragma unroll
        for (int j = 0; j < 16; ++j) {
            float x = acc[j][r] + bcv[j];
            s = fmaf(fmaxf(x, 0.0f), wsv[j], s);
        }
        s += __shfl_xor(s, 1);
        s += __shfl_xor(s, 2);
        s += __shfl_xor(s, 4);
        s += __shfl_xor(s, 8);
        if (ml == 0) g[m0 + kq * 4 + r] = s;
    }
}

// ---------------------------------------------------------------------------
// edge kernel: one thread per edge; g gathers are 4B L2 hits in a 200 KB array.
// Fast-path transcendentals only: sigmoid(raw + log(eps/(1-eps))).
// ---------------------------------------------------------------------------
__global__ __launch_bounds__(256) void edge_kernel(const float* __restrict__ g,
                                                   const int* __restrict__ edges,
                                                   const float* __restrict__ u,
                                                   const float* __restrict__ b_edge,
                                                   float* __restrict__ out) {
    const int e  = blockIdx.x * 256 + threadIdx.x;      // NE = 3125*256 exactly
    const int i0 = edges[e];
    const int i1 = edges[NE + e];
    float raw = g[i0] + g[i1] + b_edge[0];
    float uu  = u[e];
    float eps = fmaf(uu, BIASF - (1.0f - BIASF), 1.0f - BIASF); // in (1e-4, 0.9999)
    float lg  = __logf(eps) - __logf(1.0f - eps);
    float t   = __expf(-(raw + lg));
    out[e] = __fdividef(1.0f, 1.0f + t);
}

// ---------------------------------------------------------------------------
extern "C" void kernel_launch(void* const* d_in, const int* in_sizes, int n_in,
                              void* d_out, int out_size, void* d_ws, size_t ws_size,
                              hipStream_t stream) {
    const float* embedding = (const float*)d_in[0];
    const int*   edges     = (const int*)d_in[1];
    const float* u         = (const float*)d_in[2];
    const float* W_emb     = (const float*)d_in[3];
    const float* b_emb     = (const float*)d_in[4];
    const float* W_edge    = (const float*)d_in[5];
    const float* b_edge    = (const float*)d_in[6];
    float*       out       = (float*)d_out;

    // workspace layout
    char*   ws    = (char*)d_ws;
    __bf16* Wtb   = (__bf16*)ws;                      // 262,144 B
    float*  w_sym = (float*)(ws + 262144);            //   1,024 B
    float*  g     = (float*)(ws + 262144 + 1024);     // 200,000 B

    prep_kernel<<<33, 256, 0, stream>>>(W_emb, W_edge, Wtb, w_sym);

    gemm_g_kernel<<<782, 256, 0, stream>>>(embedding, Wtb, b_emb, w_sym, g);

    edge_kernel<<<NE / 256, 256, 0, stream>>>(g, edges, u, b_edge, out);
}

// Round 6
// 249.636 us; speedup vs baseline: 1.1693x; 1.1693x over previous
//
#include <hip/hip_runtime.h>
#include <hip/hip_bf16.h>

#define NN      50000
#define INDIM   512
#define HIDDEN  256
#define NE      800000
#define BIASF   0.0001f

typedef __attribute__((ext_vector_type(4))) float  f32x4;
typedef __attribute__((ext_vector_type(4))) __bf16 bf16x4;
typedef __attribute__((ext_vector_type(8))) __bf16 bf16x8;

// ---------------------------------------------------------------------------
// prep: blocks 0..31 : Wtb[n][k] = (bf16)W_emb[k][n] via coalesced LDS transpose
//       block  32    : w_sym[j] = 0.5*(We[j]+We[j+256])
// ---------------------------------------------------------------------------
__global__ __launch_bounds__(256) void prep_kernel(const float* __restrict__ W_emb,
                                                   const float* __restrict__ W_edge,
                                                   __bf16* __restrict__ Wtb,
                                                   float* __restrict__ w_sym) {
    const int b   = blockIdx.x;
    const int tid = threadIdx.x;
    if (b < 32) {
        __shared__ float t[64 * 65];
        const int kt = (b >> 2) * 64;
        const int nt = (b & 3) * 64;
        const int rr = tid >> 4;           // 0..15
        const int cc = (tid & 15) * 4;     // 0..60
#pragma unroll
        for (int p = 0; p < 4; ++p) {
            int r = p * 16 + rr;
            f32x4 v = *(const f32x4*)&W_emb[(size_t)(kt + r) * HIDDEN + nt + cc];
            t[(cc + 0) * 65 + r] = v[0];
            t[(cc + 1) * 65 + r] = v[1];
            t[(cc + 2) * 65 + r] = v[2];
            t[(cc + 3) * 65 + r] = v[3];
        }
        __syncthreads();
#pragma unroll
        for (int p = 0; p < 4; ++p) {
            int n = p * 16 + rr;
            bf16x4 o;
            o[0] = (__bf16)t[n * 65 + cc + 0];
            o[1] = (__bf16)t[n * 65 + cc + 1];
            o[2] = (__bf16)t[n * 65 + cc + 2];
            o[3] = (__bf16)t[n * 65 + cc + 3];
            *(bf16x4*)&Wtb[(size_t)(nt + n) * INDIM + kt + cc] = o;
        }
    } else {
        w_sym[tid] = 0.5f * (W_edge[tid] + W_edge[tid + HIDDEN]);
    }
}

// ---------------------------------------------------------------------------
// gemm_g v6 (resubmit — round-5 bench was an infra failure, no data):
// spill-proof barrier-free streaming. v5 post-mortem: VGPR_Count=84 + 28 MB
// WRITE_SIZE = the 160-reg design spilled to scratch under the unified cap;
// every kstep re-read B-frags from scratch (3x regression). v6 keeps the
// verified v5 operand indexing but sizes registers to ~105 < 128:
//   wave = 32 rows x 64 cols (acc 32), B single-buffered (16), A cur/nxt (32).
// Block = 4 waves = one 32-row group split into 4 N-quarters; K-loop has zero
// barriers; one 512B-LDS reduction + 1 barrier combines quarters. Grid 1563 x
// 256 thr -> 4 blocks/CU (16 waves/CU) via launch_bounds(256,4) (cap 128).
// B-traffic halves vs v5 (50000/32 waves x 64KB = 400 MB); the 4 co-resident
// quarters' per-kstep B slice = 16 KB < 32 KB L1, A rows shared by all 4
// quarters -> L1 reuse; consume order == issue order (A(ks) older than B(ks)).
//   g[m] = sum_n relu(emb[m]@W[:,n] + b[n]) * w_sym[n]
// ---------------------------------------------------------------------------
__global__ __launch_bounds__(256, 4) void gemm_g_kernel(const float* __restrict__ A,
                                                        const __bf16* __restrict__ Wtb,
                                                        const float* __restrict__ bias,
                                                        const float* __restrict__ w_sym,
                                                        float* __restrict__ g) {
    __shared__ float red[4][32];                 // 512 B only

    const int tid  = threadIdx.x;
    const int lane = tid & 63;
    const int q    = tid >> 6;                   // wave id = N-quarter (64 cols)
    const int ml   = lane & 15;                  // A row-in-set / B col-in-tile
    const int kq   = lane >> 4;                  // k-slice (x8 elems)
    const int m0   = blockIdx.x * 32;            // 1563 blocks x 32 rows = 50016

    f32x4 acc[2][4];                             // [row-set][col-tile] = 32 VGPR
#pragma unroll
    for (int s = 0; s < 2; ++s)
#pragma unroll
        for (int j = 0; j < 4; ++j) acc[s][j] = (f32x4)0.0f;

    // B: col = q*64 + j*16 + ml, k-slice kq  (v5-verified operand layout)
    const __bf16* bp[4];
#pragma unroll
    for (int j = 0; j < 4; ++j)
        bp[j] = Wtb + (size_t)(q * 64 + j * 16 + ml) * INDIM + kq * 8;

    // A: two row-sets, clamped for the 50000..50015 tail
    int gr0 = m0 + ml;      if (gr0 > NN - 1) gr0 = NN - 1;
    int gr1 = m0 + 16 + ml; if (gr1 > NN - 1) gr1 = NN - 1;
    const float* ap0 = A + (size_t)gr0 * INDIM + kq * 8;
    const float* ap1 = A + (size_t)gr1 * INDIM + kq * 8;

    // prologue: A(0) in flight
    f32x4 ac[4], an[4];
    ac[0] = *(const f32x4*)(ap0);
    ac[1] = *(const f32x4*)(ap0 + 4);
    ac[2] = *(const f32x4*)(ap1);
    ac[3] = *(const f32x4*)(ap1 + 4);

#pragma unroll
    for (int ks = 0; ks < 16; ++ks) {
        bf16x8 bf[4];
        // B(ks): 4 loads; each lane 16B, 16 cols x 1 full 64B line per instr
#pragma unroll
        for (int j = 0; j < 4; ++j)
            bf[j] = *(const bf16x8*)(bp[j] + ks * 32);
        // A(ks+1): issued young, consumed next iteration (older than B(ks+1))
        if (ks < 15) {
            an[0] = *(const f32x4*)(ap0 + (ks + 1) * 32);
            an[1] = *(const f32x4*)(ap0 + (ks + 1) * 32 + 4);
            an[2] = *(const f32x4*)(ap1 + (ks + 1) * 32);
            an[3] = *(const f32x4*)(ap1 + (ks + 1) * 32 + 4);
        }
        // cvt A(ks) (loaded last iteration) to bf16 fragments
        bf16x8 af0, af1;
#pragma unroll
        for (int i = 0; i < 4; ++i) {
            af0[i]     = (__bf16)ac[0][i];
            af0[4 + i] = (__bf16)ac[1][i];
            af1[i]     = (__bf16)ac[2][i];
            af1[4 + i] = (__bf16)ac[3][i];
        }
        // 8 MFMA: two row-sets x four col-tiles
#pragma unroll
        for (int j = 0; j < 4; ++j)
            acc[0][j] = __builtin_amdgcn_mfma_f32_16x16x32_bf16(af0, bf[j], acc[0][j], 0, 0, 0);
#pragma unroll
        for (int j = 0; j < 4; ++j)
            acc[1][j] = __builtin_amdgcn_mfma_f32_16x16x32_bf16(af1, bf[j], acc[1][j], 0, 0, 0);
#pragma unroll
        for (int i = 0; i < 4; ++i) ac[i] = an[i];
    }

    // ---- epilogue: relu + dot w_sym over this quarter's 64 cols ----
    // D layout: col = ml, row = kq*4 + r  [m89/m91, v5-verified]
    float wsv[4], bcv[4];
#pragma unroll
    for (int j = 0; j < 4; ++j) {
        int col = q * 64 + j * 16 + ml;
        wsv[j] = w_sym[col];
        bcv[j] = bias[col];
    }
#pragma unroll
    for (int s = 0; s < 2; ++s) {
#pragma unroll
        for (int r = 0; r < 4; ++r) {
            float sum = 0.0f;
#pragma unroll
            for (int j = 0; j < 4; ++j) {
                float x = acc[s][j][r] + bcv[j];
                sum = fmaf(fmaxf(x, 0.0f), wsv[j], sum);
            }
            sum += __shfl_xor(sum, 1);
            sum += __shfl_xor(sum, 2);
            sum += __shfl_xor(sum, 4);
            sum += __shfl_xor(sum, 8);
            if (ml == 0) red[q][s * 16 + kq * 4 + r] = sum;
        }
    }
    __syncthreads();
    if (tid < 32) {
        int row = m0 + tid;
        if (row < NN)
            g[row] = red[0][tid] + red[1][tid] + red[2][tid] + red[3][tid];
    }
}

// ---------------------------------------------------------------------------
// edge kernel: one thread per edge; g gathers are 4B L2 hits in a 200 KB array.
// Fast-path transcendentals only: sigmoid(raw + log(eps/(1-eps))).
// ---------------------------------------------------------------------------
__global__ __launch_bounds__(256) void edge_kernel(const float* __restrict__ g,
                                                   const int* __restrict__ edges,
                                                   const float* __restrict__ u,
                                                   const float* __restrict__ b_edge,
                                                   float* __restrict__ out) {
    const int e  = blockIdx.x * 256 + threadIdx.x;      // NE = 3125*256 exactly
    const int i0 = edges[e];
    const int i1 = edges[NE + e];
    float raw = g[i0] + g[i1] + b_edge[0];
    float uu  = u[e];
    float eps = fmaf(uu, BIASF - (1.0f - BIASF), 1.0f - BIASF); // in (1e-4, 0.9999)
    float lg  = __logf(eps) - __logf(1.0f - eps);
    float t   = __expf(-(raw + lg));
    out[e] = __fdividef(1.0f, 1.0f + t);
}

// ---------------------------------------------------------------------------
extern "C" void kernel_launch(void* const* d_in, const int* in_sizes, int n_in,
                              void* d_out, int out_size, void* d_ws, size_t ws_size,
                              hipStream_t stream) {
    const float* embedding = (const float*)d_in[0];
    const int*   edges     = (const int*)d_in[1];
    const float* u         = (const float*)d_in[2];
    const float* W_emb     = (const float*)d_in[3];
    const float* b_emb     = (const float*)d_in[4];
    const float* W_edge    = (const float*)d_in[5];
    const float* b_edge    = (const float*)d_in[6];
    float*       out       = (float*)d_out;

    // workspace layout
    char*   ws    = (char*)d_ws;
    __bf16* Wtb   = (__bf16*)ws;                      // 262,144 B
    float*  w_sym = (float*)(ws + 262144);            //   1,024 B
    float*  g     = (float*)(ws + 262144 + 1024);     // 200,000 B

    prep_kernel<<<33, 256, 0, stream>>>(W_emb, W_edge, Wtb, w_sym);

    gemm_g_kernel<<<(NN + 31) / 32, 256, 0, stream>>>(embedding, Wtb, b_emb, w_sym, g);

    edge_kernel<<<NE / 256, 256, 0, stream>>>(g, edges, u, b_edge, out);
}

// Round 7
// 246.336 us; speedup vs baseline: 1.1850x; 1.0134x over previous
//
#include <hip/hip_runtime.h>
#include <hip/hip_bf16.h>

#define NN      50000
#define INDIM   512
#define HIDDEN  256
#define NE      800000
#define BIASF   0.0001f

typedef __attribute__((ext_vector_type(4))) float  f32x4;
typedef __attribute__((ext_vector_type(4))) __bf16 bf16x4;
typedef __attribute__((ext_vector_type(8))) __bf16 bf16x8;

// ---------------------------------------------------------------------------
// prep: blocks 0..31 : Wtb[n][k] = (bf16)W_emb[k][n] via coalesced LDS transpose
//       block  32    : w_sym[j] = 0.5*(We[j]+We[j+256])
// ---------------------------------------------------------------------------
__global__ __launch_bounds__(256) void prep_kernel(const float* __restrict__ W_emb,
                                                   const float* __restrict__ W_edge,
                                                   __bf16* __restrict__ Wtb,
                                                   float* __restrict__ w_sym) {
    const int b   = blockIdx.x;
    const int tid = threadIdx.x;
    if (b < 32) {
        __shared__ float t[64 * 65];
        const int kt = (b >> 2) * 64;
        const int nt = (b & 3) * 64;
        const int rr = tid >> 4;           // 0..15
        const int cc = (tid & 15) * 4;     // 0..60
#pragma unroll
        for (int p = 0; p < 4; ++p) {
            int r = p * 16 + rr;
            f32x4 v = *(const f32x4*)&W_emb[(size_t)(kt + r) * HIDDEN + nt + cc];
            t[(cc + 0) * 65 + r] = v[0];
            t[(cc + 1) * 65 + r] = v[1];
            t[(cc + 2) * 65 + r] = v[2];
            t[(cc + 3) * 65 + r] = v[3];
        }
        __syncthreads();
#pragma unroll
        for (int p = 0; p < 4; ++p) {
            int n = p * 16 + rr;
            bf16x4 o;
            o[0] = (__bf16)t[n * 65 + cc + 0];
            o[1] = (__bf16)t[n * 65 + cc + 1];
            o[2] = (__bf16)t[n * 65 + cc + 2];
            o[3] = (__bf16)t[n * 65 + cc + 3];
            *(bf16x4*)&Wtb[(size_t)(nt + n) * INDIM + kt + cc] = o;
        }
    } else {
        w_sym[tid] = 0.5f * (W_edge[tid] + W_edge[tid + HIDDEN]);
    }
}

// ---------------------------------------------------------------------------
// gemm_g v7: v6's structure with codegen PINNED. v6 post-mortem: VGPR=44 ->
// the un-fenced scheduler sank all loads to just-in-time (load->vmcnt(0)->
// mfma x8 per kstep = 2170cy/kstep, matches the 116us exactly). v5 showed
// the opposite failure (over-hold -> spill). v7 forces the intended middle:
// register double-buffer for BOTH B (bA/bB) and A (acur/anxt), even/odd
// phase pair fully static (rule #20), sched_barrier(0) fences around each
// {prefetch}|{cvt+MFMA} phase so loads can neither sink below the fence nor
// MFMAs hoist above it. vmcnt is counted by construction: before each MFMA
// cluster the 8 loads just issued are younger -> vmcnt(8), never 0 in-loop.
// setprio(1) wraps the MFMA clusters (T5). Budget: acc 32 + bA/bB 32 +
// acur/anxt 32 + af 8 + addr ~14 = ~120 < 128 cap of launch_bounds(256,4)
// (4 blocks/CU = 16 waves/CU). Block = 4 waves x 64-col quarters, 32 rows,
// zero barriers in the K-loop, one 512B-LDS cross-quarter reduction.
//   g[m] = sum_n relu(emb[m]@W[:,n] + b[n]) * w_sym[n]
// ---------------------------------------------------------------------------
__global__ __launch_bounds__(256, 4) void gemm_g_kernel(const float* __restrict__ A,
                                                        const __bf16* __restrict__ Wtb,
                                                        const float* __restrict__ bias,
                                                        const float* __restrict__ w_sym,
                                                        float* __restrict__ g) {
    __shared__ float red[4][32];                 // 512 B only

    const int tid  = threadIdx.x;
    const int lane = tid & 63;
    const int q    = tid >> 6;                   // wave id = N-quarter (64 cols)
    const int ml   = lane & 15;                  // A row-in-set / B col-in-tile
    const int kq   = lane >> 4;                  // k-slice (x8 elems)
    const int m0   = blockIdx.x * 32;            // 1563 blocks x 32 rows

    f32x4 acc[2][4];                             // [row-set][col-tile] = 32 VGPR
#pragma unroll
    for (int s = 0; s < 2; ++s)
#pragma unroll
        for (int j = 0; j < 4; ++j) acc[s][j] = (f32x4)0.0f;

    // B: col = q*64 + j*16 + ml, k-slice kq  (verified operand layout)
    const __bf16* bp = Wtb + (size_t)(q * 64 + ml) * INDIM + kq * 8;

    // A: two row-sets, clamped for the 50000..50015 tail
    int gr0 = m0 + ml;      if (gr0 > NN - 1) gr0 = NN - 1;
    int gr1 = m0 + 16 + ml; if (gr1 > NN - 1) gr1 = NN - 1;
    const float* ap0 = A + (size_t)gr0 * INDIM + kq * 8;
    const float* ap1 = A + (size_t)gr1 * INDIM + kq * 8;

    bf16x8 bA[4], bB[4];                         // B double-buffer (static names)
    f32x4  acur[4], anxt[4];                     // A double-buffer (static names)

    // prologue: B(0) then A(0) in flight
#pragma unroll
    for (int j = 0; j < 4; ++j)
        bA[j] = *(const bf16x8*)(bp + j * 8192);
    acur[0] = *(const f32x4*)(ap0);
    acur[1] = *(const f32x4*)(ap0 + 4);
    acur[2] = *(const f32x4*)(ap1);
    acur[3] = *(const f32x4*)(ap1 + 4);
    __builtin_amdgcn_sched_barrier(0);

#pragma unroll
    for (int i = 0; i < 8; ++i) {
        const int ks = 2 * i;
        // ---- phase even: prefetch (ks+1) while computing ks ----
#pragma unroll
        for (int j = 0; j < 4; ++j)
            bB[j] = *(const bf16x8*)(bp + j * 8192 + (ks + 1) * 32);
        anxt[0] = *(const f32x4*)(ap0 + (ks + 1) * 32);
        anxt[1] = *(const f32x4*)(ap0 + (ks + 1) * 32 + 4);
        anxt[2] = *(const f32x4*)(ap1 + (ks + 1) * 32);
        anxt[3] = *(const f32x4*)(ap1 + (ks + 1) * 32 + 4);
        __builtin_amdgcn_sched_barrier(0);
        {
            bf16x8 af0, af1;
#pragma unroll
            for (int t = 0; t < 4; ++t) {
                af0[t]     = (__bf16)acur[0][t];
                af0[4 + t] = (__bf16)acur[1][t];
                af1[t]     = (__bf16)acur[2][t];
                af1[4 + t] = (__bf16)acur[3][t];
            }
            __builtin_amdgcn_s_setprio(1);
#pragma unroll
            for (int j = 0; j < 4; ++j)
                acc[0][j] = __builtin_amdgcn_mfma_f32_16x16x32_bf16(af0, bA[j], acc[0][j], 0, 0, 0);
#pragma unroll
            for (int j = 0; j < 4; ++j)
                acc[1][j] = __builtin_amdgcn_mfma_f32_16x16x32_bf16(af1, bA[j], acc[1][j], 0, 0, 0);
            __builtin_amdgcn_s_setprio(0);
        }
        __builtin_amdgcn_sched_barrier(0);

        // ---- phase odd: prefetch (ks+2) while computing ks+1 ----
        if (i < 7) {
#pragma unroll
            for (int j = 0; j < 4; ++j)
                bA[j] = *(const bf16x8*)(bp + j * 8192 + (ks + 2) * 32);
            acur[0] = *(const f32x4*)(ap0 + (ks + 2) * 32);
            acur[1] = *(const f32x4*)(ap0 + (ks + 2) * 32 + 4);
            acur[2] = *(const f32x4*)(ap1 + (ks + 2) * 32);
            acur[3] = *(const f32x4*)(ap1 + (ks + 2) * 32 + 4);
        }
        __builtin_amdgcn_sched_barrier(0);
        {
            bf16x8 af0, af1;
#pragma unroll
            for (int t = 0; t < 4; ++t) {
                af0[t]     = (__bf16)anxt[0][t];
                af0[4 + t] = (__bf16)anxt[1][t];
                af1[t]     = (__bf16)anxt[2][t];
                af1[4 + t] = (__bf16)anxt[3][t];
            }
            __builtin_amdgcn_s_setprio(1);
#pragma unroll
            for (int j = 0; j < 4; ++j)
                acc[0][j] = __builtin_amdgcn_mfma_f32_16x16x32_bf16(af0, bB[j], acc[0][j], 0, 0, 0);
#pragma unroll
            for (int j = 0; j < 4; ++j)
                acc[1][j] = __builtin_amdgcn_mfma_f32_16x16x32_bf16(af1, bB[j], acc[1][j], 0, 0, 0);
            __builtin_amdgcn_s_setprio(0);
        }
        __builtin_amdgcn_sched_barrier(0);
    }

    // ---- epilogue: relu + dot w_sym over this quarter's 64 cols ----
    // D layout: col = ml, row = kq*4 + r  [m89/m91, v5/v6-verified]
    float wsv[4], bcv[4];
#pragma unroll
    for (int j = 0; j < 4; ++j) {
        int col = q * 64 + j * 16 + ml;
        wsv[j] = w_sym[col];
        bcv[j] = bias[col];
    }
#pragma unroll
    for (int s = 0; s < 2; ++s) {
#pragma unroll
        for (int r = 0; r < 4; ++r) {
            float sum = 0.0f;
#pragma unroll
            for (int j = 0; j < 4; ++j) {
                float x = acc[s][j][r] + bcv[j];
                sum = fmaf(fmaxf(x, 0.0f), wsv[j], sum);
            }
            sum += __shfl_xor(sum, 1);
            sum += __shfl_xor(sum, 2);
            sum += __shfl_xor(sum, 4);
            sum += __shfl_xor(sum, 8);
            if (ml == 0) red[q][s * 16 + kq * 4 + r] = sum;
        }
    }
    __syncthreads();
    if (tid < 32) {
        int row = m0 + tid;
        if (row < NN)
            g[row] = red[0][tid] + red[1][tid] + red[2][tid] + red[3][tid];
    }
}

// ---------------------------------------------------------------------------
// edge kernel: one thread per edge; g gathers are 4B L2 hits in a 200 KB array.
// Fast-path transcendentals only: sigmoid(raw + log(eps/(1-eps))).
// ---------------------------------------------------------------------------
__global__ __launch_bounds__(256) void edge_kernel(const float* __restrict__ g,
                                                   const int* __restrict__ edges,
                                                   const float* __restrict__ u,
                                                   const float* __restrict__ b_edge,
                                                   float* __restrict__ out) {
    const int e  = blockIdx.x * 256 + threadIdx.x;      // NE = 3125*256 exactly
    const int i0 = edges[e];
    const int i1 = edges[NE + e];
    float raw = g[i0] + g[i1] + b_edge[0];
    float uu  = u[e];
    float eps = fmaf(uu, BIASF - (1.0f - BIASF), 1.0f - BIASF); // in (1e-4, 0.9999)
    float lg  = __logf(eps) - __logf(1.0f - eps);
    float t   = __expf(-(raw + lg));
    out[e] = __fdividef(1.0f, 1.0f + t);
}

// ---------------------------------------------------------------------------
extern "C" void kernel_launch(void* const* d_in, const int* in_sizes, int n_in,
                              void* d_out, int out_size, void* d_ws, size_t ws_size,
                              hipStream_t stream) {
    const float* embedding = (const float*)d_in[0];
    const int*   edges     = (const int*)d_in[1];
    const float* u         = (const float*)d_in[2];
    const float* W_emb     = (const float*)d_in[3];
    const float* b_emb     = (const float*)d_in[4];
    const float* W_edge    = (const float*)d_in[5];
    const float* b_edge    = (const float*)d_in[6];
    float*       out       = (float*)d_out;

    // workspace layout
    char*   ws    = (char*)d_ws;
    __bf16* Wtb   = (__bf16*)ws;                      // 262,144 B
    float*  w_sym = (float*)(ws + 262144);            //   1,024 B
    float*  g     = (float*)(ws + 262144 + 1024);     // 200,000 B

    prep_kernel<<<33, 256, 0, stream>>>(W_emb, W_edge, Wtb, w_sym);

    gemm_g_kernel<<<(NN + 31) / 32, 256, 0, stream>>>(embedding, Wtb, b_emb, w_sym, g);

    edge_kernel<<<NE / 256, 256, 0, stream>>>(g, edges, u, b_edge, out);
}

// Round 10
// 226.623 us; speedup vs baseline: 1.2880x; 1.0870x over previous
//
#include <hip/hip_runtime.h>
#include <hip/hip_bf16.h>

#define NN      50000
#define INDIM   512
#define HIDDEN  256
#define NE      800000
#define BIASF   0.0001f

typedef __attribute__((ext_vector_type(4))) float  f32x4;
typedef __attribute__((ext_vector_type(4))) __bf16 bf16x4;
typedef __attribute__((ext_vector_type(8))) __bf16 bf16x8;

// async global->LDS DMA, 16 B per lane, wave-uniform LDS base + lane*16 [m97]
__device__ __forceinline__ void async_copy16(const float* gp, float* lp) {
    __builtin_amdgcn_global_load_lds(
        (const __attribute__((address_space(1))) void*)gp,
        (__attribute__((address_space(3))) void*)lp,
        16, 0, 0);
}

// ---------------------------------------------------------------------------
// prep: blocks 0..31 : Wtb[n][k] = (bf16)W_emb[k][n] via coalesced LDS transpose
//       block  32    : w_sym[j] = 0.5*(We[j]+We[j+256])
// ---------------------------------------------------------------------------
__global__ __launch_bounds__(256) void prep_kernel(const float* __restrict__ W_emb,
                                                   const float* __restrict__ W_edge,
                                                   __bf16* __restrict__ Wtb,
                                                   float* __restrict__ w_sym) {
    const int b   = blockIdx.x;
    const int tid = threadIdx.x;
    if (b < 32) {
        __shared__ float t[64 * 65];
        const int kt = (b >> 2) * 64;
        const int nt = (b & 3) * 64;
        const int rr = tid >> 4;           // 0..15
        const int cc = (tid & 15) * 4;     // 0..60
#pragma unroll
        for (int p = 0; p < 4; ++p) {
            int r = p * 16 + rr;
            f32x4 v = *(const f32x4*)&W_emb[(size_t)(kt + r) * HIDDEN + nt + cc];
            t[(cc + 0) * 65 + r] = v[0];
            t[(cc + 1) * 65 + r] = v[1];
            t[(cc + 2) * 65 + r] = v[2];
            t[(cc + 3) * 65 + r] = v[3];
        }
        __syncthreads();
#pragma unroll
        for (int p = 0; p < 4; ++p) {
            int n = p * 16 + rr;
            bf16x4 o;
            o[0] = (__bf16)t[n * 65 + cc + 0];
            o[1] = (__bf16)t[n * 65 + cc + 1];
            o[2] = (__bf16)t[n * 65 + cc + 2];
            o[3] = (__bf16)t[n * 65 + cc + 3];
            *(bf16x4*)&Wtb[(size_t)(nt + n) * INDIM + kt + cc] = o;
        }
    } else {
        w_sym[tid] = 0.5f * (W_edge[tid] + W_edge[tid + HIDDEN]);
    }
}

// ---------------------------------------------------------------------------
// gemm_g v8b: v8 design, minimally perturbed after two consecutive container
// failures on identical v8 source (audit found no hang/OOB/race; this build
// removes the only zero-expected-value exotic construct -- 32 in-loop
// s_setprio toggles [T5 is measured-null without phase role-split, m190] --
// and hoists loop-invariant addresses). Design recap:
//   A staged via global_load_lds into PER-WAVE-PRIVATE double-buffered LDS
//   tiles (4 KB each) => zero __syncthreads in the K-loop; A never transits
//   VGPRs (v5/v6/v7 all died on A+B register pressure: spill or JIT collapse).
//   B bf16x8 frags from L2-hot Wtb, register double-buffer w/ static names.
//   Per chunk c: issue {4 DMA + 4 B} for c+1, then asm s_waitcnt vmcnt(8) --
//   architectural fence, exact by construction (drains chunk c's 8, keeps
//   c+1's 8 in flight; never vmcnt(0) in-loop [T4]). DMA->ds_read is the only
//   compiler-invisible dep and is exactly what the fence orders.
//   Swizzle: linear LDS dest + pre-XOR'd GLOBAL source [m173], read-side
//   byte ^ ((ml&7)<<4) => 2-way bank alias = free [m136]; round-trip verified
//   (write block b^(r&7), read block (kq*2+h)^(ml&7) of row ml => identity).
// Regs: acc 32 + bfA/bfB 32 + af 8 + ptrs ~16 => ~105 < 128 cap (256,4);
// LDS 33.25 KB => 4 blocks/CU = 16 waves/CU.
//   g[m] = sum_n relu(emb[m]@W[:,n] + b[n]) * w_sym[n]
// ---------------------------------------------------------------------------
__global__ __launch_bounds__(256, 4) void gemm_g_kernel(const float* __restrict__ A,
                                                        const __bf16* __restrict__ Wtb,
                                                        const float* __restrict__ bias,
                                                        const float* __restrict__ w_sym,
                                                        float* __restrict__ g) {
    __shared__ __align__(16) float As[4][2][1024];   // [wave][buf][32r x 32k f32]
    __shared__ float red[4][32];                     // 512 B cross-wave reduce

    const int tid  = threadIdx.x;
    const int lane = tid & 63;
    const int w    = tid >> 6;                   // wave id = N-quarter (64 cols)
    const int ml   = lane & 15;                  // B col-in-tile / A row (and +16)
    const int kq   = lane >> 4;                  // k-slice (x8 f32)
    const int m0   = blockIdx.x * 32;            // 1563 x 32 = 50016 (guarded)

    f32x4 acc[2][4];                             // [row-set][col-tile] = 32 VGPR
#pragma unroll
    for (int s = 0; s < 2; ++s)
#pragma unroll
        for (int j = 0; j < 4; ++j) acc[s][j] = (f32x4)0.0f;

    // B: col = w*64 + j*16 + ml, k-slice kq (verified operand layout)
    const __bf16* bp[4];
#pragma unroll
    for (int j = 0; j < 4; ++j)
        bp[j] = Wtb + (size_t)(w * 64 + j * 16 + ml) * INDIM + kq * 8;

    // DMA sources: pass p stages rows p*8+(lane>>3); within-row f32 offset
    // (lane&7)*4 pre-XOR'd with ((row&7)<<2) so linear LDS + XOR read match.
    const float* gsrc[4];
#pragma unroll
    for (int p = 0; p < 4; ++p) {
        int row = p * 8 + (lane >> 3);
        int gr  = m0 + row; if (gr > NN - 1) gr = NN - 1;    // M-tail clamp
        gsrc[p] = A + (size_t)gr * INDIM + (((lane & 7) * 4) ^ ((row & 7) << 2));
    }

    // loop-invariant read-side addresses (16B-aligned by construction)
    const int swz = (ml & 7) << 4;
    const int o00 = (ml * 128 + kq * 32) ^ swz;              // row ml, lo
    const int o01 = (ml * 128 + kq * 32 + 16) ^ swz;         // row ml, hi
    const int o10 = ((ml + 16) * 128 + kq * 32) ^ swz;       // row ml+16, lo
    const int o11 = ((ml + 16) * 128 + kq * 32 + 16) ^ swz;  // row ml+16, hi

    bf16x8 bfA[4], bfB[4];                       // B double-buffer, static names

    // ---- prologue: chunk 0 in flight (4 DMA + 4 B = 8 VMEM) ----
#pragma unroll
    for (int p = 0; p < 4; ++p)
        async_copy16(gsrc[p], &As[w][0][p * 256]);
#pragma unroll
    for (int j = 0; j < 4; ++j)
        bfA[j] = *(const bf16x8*)(bp[j]);

#pragma unroll
    for (int c = 0; c < 16; ++c) {               // 16 chunks of K=32
        if (c < 15) {
            // prefetch chunk c+1: 4 DMA into the other buffer + 4 B-frags
#pragma unroll
            for (int p = 0; p < 4; ++p)
                async_copy16(gsrc[p] + (c + 1) * 32, &As[w][(c + 1) & 1][p * 256]);
            if ((c & 1) == 0) {
#pragma unroll
                for (int j = 0; j < 4; ++j)
                    bfB[j] = *(const bf16x8*)(bp[j] + (c + 1) * 32);
            } else {
#pragma unroll
                for (int j = 0; j < 4; ++j)
                    bfA[j] = *(const bf16x8*)(bp[j] + (c + 1) * 32);
            }
            // exact-count fence: drains chunk c's 8, keeps c+1's 8 flying
            asm volatile("s_waitcnt vmcnt(8)" ::: "memory");
        } else {
            asm volatile("s_waitcnt vmcnt(0)" ::: "memory");
        }
        __builtin_amdgcn_sched_barrier(0);

        // ---- compute chunk c: pure LDS+cvt+MFMA, buffer c&1 ----
        const char* lb = (const char*)&As[w][c & 1][0];
        f32x4 lo0 = *(const f32x4*)(lb + o00);
        f32x4 hi0 = *(const f32x4*)(lb + o01);
        f32x4 lo1 = *(const f32x4*)(lb + o10);
        f32x4 hi1 = *(const f32x4*)(lb + o11);
        bf16x8 af0, af1;
#pragma unroll
        for (int t = 0; t < 4; ++t) {
            af0[t]     = (__bf16)lo0[t];
            af0[4 + t] = (__bf16)hi0[t];
            af1[t]     = (__bf16)lo1[t];
            af1[4 + t] = (__bf16)hi1[t];
        }
        if ((c & 1) == 0) {
#pragma unroll
            for (int j = 0; j < 4; ++j)
                acc[0][j] = __builtin_amdgcn_mfma_f32_16x16x32_bf16(af0, bfA[j], acc[0][j], 0, 0, 0);
#pragma unroll
            for (int j = 0; j < 4; ++j)
                acc[1][j] = __builtin_amdgcn_mfma_f32_16x16x32_bf16(af1, bfA[j], acc[1][j], 0, 0, 0);
        } else {
#pragma unroll
            for (int j = 0; j < 4; ++j)
                acc[0][j] = __builtin_amdgcn_mfma_f32_16x16x32_bf16(af0, bfB[j], acc[0][j], 0, 0, 0);
#pragma unroll
            for (int j = 0; j < 4; ++j)
                acc[1][j] = __builtin_amdgcn_mfma_f32_16x16x32_bf16(af1, bfB[j], acc[1][j], 0, 0, 0);
        }
        __builtin_amdgcn_sched_barrier(0);
    }

    // ---- epilogue: relu + dot w_sym over this wave's 64 cols ----
    // D layout: col = ml, row = kq*4 + r (+16 for row-set 1) [m89/m91]
    float wsv[4], bcv[4];
#pragma unroll
    for (int j = 0; j < 4; ++j) {
        int col = w * 64 + j * 16 + ml;
        wsv[j] = w_sym[col];
        bcv[j] = bias[col];
    }
#pragma unroll
    for (int s = 0; s < 2; ++s) {
#pragma unroll
        for (int r = 0; r < 4; ++r) {
            float sum = 0.0f;
#pragma unroll
            for (int j = 0; j < 4; ++j) {
                float x = acc[s][j][r] + bcv[j];
                sum = fmaf(fmaxf(x, 0.0f), wsv[j], sum);
            }
            sum += __shfl_xor(sum, 1);
            sum += __shfl_xor(sum, 2);
            sum += __shfl_xor(sum, 4);
            sum += __shfl_xor(sum, 8);
            if (ml == 0) red[w][s * 16 + kq * 4 + r] = sum;
        }
    }
    __syncthreads();
    if (tid < 32) {
        int row = m0 + tid;
        if (row < NN)
            g[row] = red[0][tid] + red[1][tid] + red[2][tid] + red[3][tid];
    }
}

// ---------------------------------------------------------------------------
// edge kernel: one thread per edge; g gathers are 4B L2 hits in a 200 KB array.
// Fast-path transcendentals only: sigmoid(raw + log(eps/(1-eps))).
// ---------------------------------------------------------------------------
__global__ __launch_bounds__(256) void edge_kernel(const float* __restrict__ g,
                                                   const int* __restrict__ edges,
                                                   const float* __restrict__ u,
                                                   const float* __restrict__ b_edge,
                                                   float* __restrict__ out) {
    const int e  = blockIdx.x * 256 + threadIdx.x;      // NE = 3125*256 exactly
    const int i0 = edges[e];
    const int i1 = edges[NE + e];
    float raw = g[i0] + g[i1] + b_edge[0];
    float uu  = u[e];
    float eps = fmaf(uu, BIASF - (1.0f - BIASF), 1.0f - BIASF); // in (1e-4, 0.9999)
    float lg  = __logf(eps) - __logf(1.0f - eps);
    float t   = __expf(-(raw + lg));
    out[e] = __fdividef(1.0f, 1.0f + t);
}

// ---------------------------------------------------------------------------
extern "C" void kernel_launch(void* const* d_in, const int* in_sizes, int n_in,
                              void* d_out, int out_size, void* d_ws, size_t ws_size,
                              hipStream_t stream) {
    const float* embedding = (const float*)d_in[0];
    const int*   edges     = (const int*)d_in[1];
    const float* u         = (const float*)d_in[2];
    const float* W_emb     = (const float*)d_in[3];
    const float* b_emb     = (const float*)d_in[4];
    const float* W_edge    = (const float*)d_in[5];
    const float* b_edge    = (const float*)d_in[6];
    float*       out       = (float*)d_out;

    // workspace layout
    char*   ws    = (char*)d_ws;
    __bf16* Wtb   = (__bf16*)ws;                      // 262,144 B
    float*  w_sym = (float*)(ws + 262144);            //   1,024 B
    float*  g     = (float*)(ws + 262144 + 1024);     // 200,000 B

    prep_kernel<<<33, 256, 0, stream>>>(W_emb, W_edge, Wtb, w_sym);

    gemm_g_kernel<<<(NN + 31) / 32, 256, 0, stream>>>(embedding, Wtb, b_emb, w_sym, g);

    edge_kernel<<<NE / 256, 256, 0, stream>>>(g, edges, u, b_edge, out);
}

// Round 11
// 194.566 us; speedup vs baseline: 1.5003x; 1.1648x over previous
//
#include <hip/hip_runtime.h>
#include <hip/hip_bf16.h>

#define NN      50000
#define INDIM   512
#define HIDDEN  256
#define NE      800000
#define BIASF   0.0001f

typedef __attribute__((ext_vector_type(4))) float  f32x4;
typedef __attribute__((ext_vector_type(4))) __bf16 bf16x4;
typedef __attribute__((ext_vector_type(8))) __bf16 bf16x8;

// ---------------------------------------------------------------------------
// prep: blocks 0..31 : Wtb[n][k] = (bf16)W_emb[k][n] via coalesced LDS transpose
//       block  32    : w_sym[j] = 0.5*(We[j]+We[j+256])
// ---------------------------------------------------------------------------
__global__ __launch_bounds__(256) void prep_kernel(const float* __restrict__ W_emb,
                                                   const float* __restrict__ W_edge,
                                                   __bf16* __restrict__ Wtb,
                                                   float* __restrict__ w_sym) {
    const int b   = blockIdx.x;
    const int tid = threadIdx.x;
    if (b < 32) {
        __shared__ float t[64 * 65];
        const int kt = (b >> 2) * 64;
        const int nt = (b & 3) * 64;
        const int rr = tid >> 4;           // 0..15
        const int cc = (tid & 15) * 4;     // 0..60
#pragma unroll
        for (int p = 0; p < 4; ++p) {
            int r = p * 16 + rr;
            f32x4 v = *(const f32x4*)&W_emb[(size_t)(kt + r) * HIDDEN + nt + cc];
            t[(cc + 0) * 65 + r] = v[0];
            t[(cc + 1) * 65 + r] = v[1];
            t[(cc + 2) * 65 + r] = v[2];
            t[(cc + 3) * 65 + r] = v[3];
        }
        __syncthreads();
#pragma unroll
        for (int p = 0; p < 4; ++p) {
            int n = p * 16 + rr;
            bf16x4 o;
            o[0] = (__bf16)t[n * 65 + cc + 0];
            o[1] = (__bf16)t[n * 65 + cc + 1];
            o[2] = (__bf16)t[n * 65 + cc + 2];
            o[3] = (__bf16)t[n * 65 + cc + 3];
            *(bf16x4*)&Wtb[(size_t)(nt + n) * INDIM + kt + cc] = o;
        }
    } else {
        w_sym[tid] = 0.5f * (W_edge[tid] + W_edge[tid + HIDDEN]);
    }
}

// ---------------------------------------------------------------------------
// gemm_g v9: the best-measured skeleton (v4 block-cooperative, 188.1 us total)
// regeometrized for pass quantization. Session ledger: block-cooperative
// 78->70->67->~55 us; per-wave streaming 162/116/113/91 us (register-resident
// B is always dismantled by the allocator: spill at 160 regs, JIT collapse at
// 44-56 regs, even against asm vmcnt fences). All variants are block-latency
// bound (all pipes <10%), so wall ~= passes x block-lifetime. v4: 782 blocks
// at 2 blocks/CU = 512 slots -> 1.53 passes (2nd pass half-empty). v9: 256
// thr / 4 waves, BM=64 (wave = 64 rows x 64 cols, acc 4x4), K-chunks of 64,
// LDS 17.4 KB, launch_bounds(256,3) -> 3 blocks/CU = 768 slots -> 782 blocks
// = 1.02 passes. Same verified v4 load-order (loadB(c+1) issued BEFORE
// stage_load(c+2): B waits never drain the A prefetch [m135 in-order vmcnt]);
// same v2-verified swizzle (byte ^ ((row&7)<<4), 2-way = free [m136]) and
// epilogue. Regs ~154 < 170 cap @ 12 waves/CU.
//   g[m] = sum_n relu(emb[m]@W[:,n] + b[n]) * w_sym[n]
// ---------------------------------------------------------------------------
__global__ __launch_bounds__(256, 3) void gemm_g_kernel(const float* __restrict__ A,
                                                        const __bf16* __restrict__ Wtb,
                                                        const float* __restrict__ bias,
                                                        const float* __restrict__ w_sym,
                                                        float* __restrict__ g) {
    __shared__ __align__(16) __bf16 As[2][64 * 64];  // 2 x 8 KiB bf16
    __shared__ float red[4][64];                     // 1 KiB

    const int tid  = threadIdx.x;
    const int lane = tid & 63;
    const int w    = tid >> 6;                   // wave id = col-quarter (64 cols)
    const int ml   = lane & 15;                  // frag row/col within tile
    const int kq   = lane >> 4;                  // k-slice (x8 elems)
    const int m0   = blockIdx.x * 64;            // 782 x 64 = 50048 (guarded)

    f32x4 acc[4][4];                             // [row-set][col-tile] = 64 VGPR
#pragma unroll
    for (int i = 0; i < 4; ++i)
#pragma unroll
        for (int j = 0; j < 4; ++j) acc[i][j] = (f32x4)0.0f;

    // B: col = w*64 + nt*16 + ml, k-slice kq (operand layout verified v4-v8)
    const __bf16* bp[4];
#pragma unroll
    for (int nt = 0; nt < 4; ++nt)
        bp[nt] = Wtb + (size_t)(w * 64 + nt * 16 + ml) * INDIM + kq * 8;

    // A staging: thread covers rows j*16 + (tid>>4), f32 cols (tid&15)*4..+3
    const int srow = tid >> 4;                   // 0..15
    const int scol = (tid & 15) * 4;             // f32 col 0..60
    const float* ap[4];
#pragma unroll
    for (int j = 0; j < 4; ++j) {
        int gr = m0 + j * 16 + srow;
        if (gr > NN - 1) gr = NN - 1;            // M-tail clamp
        ap[j] = A + (size_t)gr * INDIM + scol;
    }

    auto stage_load = [&](f32x4* st, int c) {
#pragma unroll
        for (int j = 0; j < 4; ++j)
            st[j] = *(const f32x4*)(ap[j] + c * 64);
    };
    // cvt to bf16, write 8B at swizzled slot (row stride 128 B)
    auto stage_write = [&](const f32x4* st, int b) {
        char* lb = (char*)&As[b][0];
#pragma unroll
        for (int j = 0; j < 4; ++j) {
            int r = j * 16 + srow;
            bf16x4 o;
            o[0] = (__bf16)st[j][0]; o[1] = (__bf16)st[j][1];
            o[2] = (__bf16)st[j][2]; o[3] = (__bf16)st[j][3];
            *(bf16x4*)(lb + ((r * 128 + scol * 2) ^ ((r & 7) << 4))) = o;
        }
    };
    // hoist this chunk's B (64 cols x 64 k) into 32 VGPRs from L2-hot Wtb
    auto loadB = [&](bf16x8* bfr, int c) {
#pragma unroll
        for (int ks = 0; ks < 2; ++ks)
#pragma unroll
            for (int nt = 0; nt < 4; ++nt)
                bfr[ks * 4 + nt] = *(const bf16x8*)(bp[nt] + c * 64 + ks * 32);
    };
    // pure LDS+MFMA: 2 ksteps of K=32, 4 row-sets x 4 col-tiles
    auto compute = [&](int b, const bf16x8* bfr) {
        const char* lb = (const char*)&As[b][0];
#pragma unroll
        for (int ks = 0; ks < 2; ++ks) {
            bf16x8 af[4];
#pragma unroll
            for (int mt = 0; mt < 4; ++mt) {
                int r = mt * 16 + ml;
                af[mt] = *(const bf16x8*)(lb + ((r * 128 + ks * 64 + kq * 16)
                                                ^ ((r & 7) << 4)));
            }
#pragma unroll
            for (int mt = 0; mt < 4; ++mt)
#pragma unroll
                for (int nt = 0; nt < 4; ++nt)
                    acc[mt][nt] = __builtin_amdgcn_mfma_f32_16x16x32_bf16(
                        af[mt], bfr[ks * 4 + nt], acc[mt][nt], 0, 0, 0);
        }
    };

    f32x4  st[4];                                // 16 VGPR A staging
    bf16x8 bfr[8];                               // 32 VGPR B chunk

    stage_load(st, 0);
    stage_write(st, 0);                          // vmcnt reg-dep drains A0
    __syncthreads();                             // tile 0 visible
    loadB(bfr, 0);                               // B0 oldest in queue
    stage_load(st, 1);                           // A1 younger; flies over compute(0)

#pragma unroll
    for (int c = 0; c < 8; ++c) {                // 8 chunks of K=64
        compute(c & 1, bfr);
        if (c < 7) {
            loadB(bfr, c + 1);                   // B(c+1) BEFORE A(c+2): in-order
            stage_write(st, (c + 1) & 1);        //   queue keeps A prefetch flying
            __syncthreads();
            if (c < 6) stage_load(st, c + 2);
        }
    }

    // ---- epilogue: relu + dot w_sym over this wave's 64 cols ----
    // D layout: col = ml, row = kq*4 + r (+mt*16) [m89/m91, verified v4-v8]
    float wsv[4], bcv[4];
#pragma unroll
    for (int nt = 0; nt < 4; ++nt) {
        int col = w * 64 + nt * 16 + ml;
        wsv[nt] = w_sym[col];
        bcv[nt] = bias[col];
    }
#pragma unroll
    for (int mt = 0; mt < 4; ++mt) {
#pragma unroll
        for (int r = 0; r < 4; ++r) {
            float s = 0.0f;
#pragma unroll
            for (int nt = 0; nt < 4; ++nt) {
                float x = acc[mt][nt][r] + bcv[nt];
                s = fmaf(fmaxf(x, 0.0f), wsv[nt], s);
            }
            s += __shfl_xor(s, 1);
            s += __shfl_xor(s, 2);
            s += __shfl_xor(s, 4);
            s += __shfl_xor(s, 8);
            if (ml == 0) red[w][mt * 16 + kq * 4 + r] = s;
        }
    }
    __syncthreads();
    if (tid < 64) {
        int row = m0 + tid;
        if (row < NN)
            g[row] = red[0][tid] + red[1][tid] + red[2][tid] + red[3][tid];
    }
}

// ---------------------------------------------------------------------------
// edge kernel: one thread per edge; g gathers are 4B L2 hits in a 200 KB array.
// Fast-path transcendentals only: sigmoid(raw + log(eps/(1-eps))).
// ---------------------------------------------------------------------------
__global__ __launch_bounds__(256) void edge_kernel(const float* __restrict__ g,
                                                   const int* __restrict__ edges,
                                                   const float* __restrict__ u,
                                                   const float* __restrict__ b_edge,
                                                   float* __restrict__ out) {
    const int e  = blockIdx.x * 256 + threadIdx.x;      // NE = 3125*256 exactly
    const int i0 = edges[e];
    const int i1 = edges[NE + e];
    float raw = g[i0] + g[i1] + b_edge[0];
    float uu  = u[e];
    float eps = fmaf(uu, BIASF - (1.0f - BIASF), 1.0f - BIASF); // in (1e-4, 0.9999)
    float lg  = __logf(eps) - __logf(1.0f - eps);
    float t   = __expf(-(raw + lg));
    out[e] = __fdividef(1.0f, 1.0f + t);
}

// ---------------------------------------------------------------------------
extern "C" void kernel_launch(void* const* d_in, const int* in_sizes, int n_in,
                              void* d_out, int out_size, void* d_ws, size_t ws_size,
                              hipStream_t stream) {
    const float* embedding = (const float*)d_in[0];
    const int*   edges     = (const int*)d_in[1];
    const float* u         = (const float*)d_in[2];
    const float* W_emb     = (const float*)d_in[3];
    const float* b_emb     = (const float*)d_in[4];
    const float* W_edge    = (const float*)d_in[5];
    const float* b_edge    = (const float*)d_in[6];
    float*       out       = (float*)d_out;

    // workspace layout
    char*   ws    = (char*)d_ws;
    __bf16* Wtb   = (__bf16*)ws;                      // 262,144 B
    float*  w_sym = (float*)(ws + 262144);            //   1,024 B
    float*  g     = (float*)(ws + 262144 + 1024);     // 200,000 B

    prep_kernel<<<33, 256, 0, stream>>>(W_emb, W_edge, Wtb, w_sym);

    gemm_g_kernel<<<(NN + 63) / 64, 256, 0, stream>>>(embedding, Wtb, b_emb, w_sym, g);

    edge_kernel<<<NE / 256, 256, 0, stream>>>(g, edges, u, b_edge, out);
}